// Round 1
// baseline (493.102 us; speedup 1.0000x reference)
//
#include <hip/hip_runtime.h>

#define PCOLS 1536  // per-branch projection width: q512 | k512 | v512

typedef short s16x8 __attribute__((ext_vector_type(8)));
typedef float f32x4 __attribute__((ext_vector_type(4)));

#define MFMA16(a, b, c) __builtin_amdgcn_mfma_f32_16x16x32_bf16((a), (b), (c), 0, 0, 0)

__device__ __forceinline__ unsigned short f2b(float f) {
  union { float f; unsigned int u; } v; v.f = f;
  unsigned int u = v.u;
  unsigned int r = (u + 0x7fffu + ((u >> 16) & 1u)) >> 16;  // RNE
  return (unsigned short)r;
}
__device__ __forceinline__ float b2f(unsigned short b) {
  union { unsigned int u; float f; } v; v.u = ((unsigned int)b) << 16;
  return v.f;
}

// ---------------- prep ----------------
__global__ __launch_bounds__(256) void cvt_x(const float* __restrict__ x,
                                             unsigned short* __restrict__ xb) {
  size_t i = ((size_t)blockIdx.x * 256 + threadIdx.x) * 4;
  float4 v = *(const float4*)(x + i);
  ushort4 o;
  o.x = f2b(v.x); o.y = f2b(v.y); o.z = f2b(v.z); o.w = f2b(v.w);
  *(ushort4*)(xb + i) = o;
}

// WcatT[n][k] = W[k][n], n in [0,3072): [wq | wkv | hq | hkv]
__global__ __launch_bounds__(256) void build_wt(const float* __restrict__ wq,
                                                const float* __restrict__ wkv,
                                                const float* __restrict__ hq,
                                                const float* __restrict__ hkv,
                                                unsigned short* __restrict__ WT) {
  const int n = blockIdx.x, k = threadIdx.x;
  float v;
  if (n < 512)       v = wq [(size_t)k * 512  + n];
  else if (n < 1536) v = wkv[(size_t)k * 1024 + (n - 512)];
  else if (n < 2048) v = hq [(size_t)k * 512  + (n - 1536)];
  else               v = hkv[(size_t)k * 1024 + (n - 2048)];
  WT[(size_t)n * 256 + k] = f2b(v);
}

// W2T[n][k] = [wout;hout][k][n], n<256, k<1024
__global__ __launch_bounds__(256) void build_w2t(const float* __restrict__ wout,
                                                 const float* __restrict__ hout,
                                                 unsigned short* __restrict__ W2T) {
  const int n = blockIdx.x;
  for (int k = threadIdx.x; k < 1024; k += 256) {
    const float v = (k < 512) ? wout[(size_t)k * 256 + n] : hout[(size_t)(k - 512) * 256 + n];
    W2T[(size_t)n * 1024 + k] = f2b(v);
  }
}

// ---------------- QKV projection: C(32768x1536) = X(32768x256) @ W^T ----------------
__global__ __launch_bounds__(256) void gemm_proj(const unsigned short* __restrict__ X,
                                                 const unsigned short* __restrict__ WT,
                                                 unsigned short* __restrict__ C) {
  const int tid = threadIdx.x, wave = tid >> 6, lane = tid & 63;
  const int q = lane >> 4, l = lane & 15;
  const int m0 = blockIdx.x * 128 + (wave >> 1) * 64;
  const int n0 = blockIdx.y * 128 + (wave & 1) * 64;
  f32x4 acc[4][4] = {};
#pragma unroll
  for (int ks = 0; ks < 8; ++ks) {
    const int kk = ks * 32 + q * 8;
    s16x8 a[4], b[4];
#pragma unroll
    for (int i = 0; i < 4; ++i) a[i] = *(const s16x8*)(X + (size_t)(m0 + i * 16 + l) * 256 + kk);
#pragma unroll
    for (int j = 0; j < 4; ++j) b[j] = *(const s16x8*)(WT + (size_t)(n0 + j * 16 + l) * 256 + kk);
#pragma unroll
    for (int i = 0; i < 4; ++i)
#pragma unroll
      for (int j = 0; j < 4; ++j) acc[i][j] = MFMA16(a[i], b[j], acc[i][j]);
  }
#pragma unroll
  for (int i = 0; i < 4; ++i)
#pragma unroll
    for (int j = 0; j < 4; ++j) {
      const int row = m0 + i * 16 + q * 4, col = n0 + j * 16 + l;
      unsigned short* p = C + (size_t)row * PCOLS + col;
#pragma unroll
      for (int r = 0; r < 4; ++r) p[(size_t)r * PCOLS] = f2b(acc[i][j][r]);
    }
}

// ---------------- column attention: one block per (w, H) ----------------
__global__ __launch_bounds__(256) void col_attn(const unsigned short* __restrict__ C,
                                                unsigned short* __restrict__ O) {
  __shared__ unsigned short Sp[128 * 136];  // logits -> P (bf16)
  __shared__ unsigned short Vt[64 * 136];   // V^T
  __shared__ float rowinv[128];
  const int w = blockIdx.x, H = blockIdx.y;
  const int tid = threadIdx.x, wave = tid >> 6, lane = tid & 63;
  const int q = lane >> 4, l = lane & 15;
  const unsigned short* Qp = C + H * 64;
  const unsigned short* Kp = C + 512 + H * 64;
  const unsigned short* Vp = C + 1024 + H * 64;
  // stage V^T: Vt[d][j] = V[j][d]   (j = seq pos in column, row of x = j*256+w)
  for (int u = tid; u < 1024; u += 256) {
    const int j = u >> 3, db = u & 7;
    s16x8 v = *(const s16x8*)(Vp + (size_t)(j * 256 + w) * PCOLS + db * 8);
#pragma unroll
    for (int t = 0; t < 8; ++t) Vt[(db * 8 + t) * 136 + j] = v[t];
  }
  // S = q k^T * scale; wave handles 32 rows
  {
    const int m0 = wave * 32;
    f32x4 acc[2][8] = {};
#pragma unroll
    for (int ks = 0; ks < 2; ++ks) {
      const int kk = ks * 32 + q * 8;
      s16x8 a[2], b[8];
#pragma unroll
      for (int i = 0; i < 2; ++i)
        a[i] = *(const s16x8*)(Qp + (size_t)((m0 + i * 16 + l) * 256 + w) * PCOLS + kk);
#pragma unroll
      for (int j = 0; j < 8; ++j)
        b[j] = *(const s16x8*)(Kp + (size_t)((j * 16 + l) * 256 + w) * PCOLS + kk);
#pragma unroll
      for (int i = 0; i < 2; ++i)
#pragma unroll
        for (int j = 0; j < 8; ++j) acc[i][j] = MFMA16(a[i], b[j], acc[i][j]);
    }
#pragma unroll
    for (int i = 0; i < 2; ++i)
#pragma unroll
      for (int j = 0; j < 8; ++j)
#pragma unroll
        for (int r = 0; r < 4; ++r)
          Sp[(m0 + i * 16 + q * 4 + r) * 136 + j * 16 + l] = f2b(acc[i][j][r] * 0.125f);
  }
  __syncthreads();
  // softmax per row (unnormalized P in LDS; 1/sum folded into epilogue)
  if (tid < 128) {
    float mx = -1e30f;
    for (int j = 0; j < 128; ++j) mx = fmaxf(mx, b2f(Sp[tid * 136 + j]));
    float s = 0.f;
    for (int j = 0; j < 128; ++j) {
      float e = __expf(b2f(Sp[tid * 136 + j]) - mx);
      s += e;
      Sp[tid * 136 + j] = f2b(e);
    }
    rowinv[tid] = 1.0f / s;
  }
  __syncthreads();
  // O = P @ V
  {
    const int m0 = wave * 32;
    f32x4 acc[2][4] = {};
#pragma unroll
    for (int ks = 0; ks < 4; ++ks) {
      const int kk = ks * 32 + q * 8;
      s16x8 a[2], b[4];
#pragma unroll
      for (int i = 0; i < 2; ++i) a[i] = *(const s16x8*)(&Sp[(m0 + i * 16 + l) * 136 + kk]);
#pragma unroll
      for (int j = 0; j < 4; ++j) b[j] = *(const s16x8*)(&Vt[(j * 16 + l) * 136 + kk]);
#pragma unroll
      for (int i = 0; i < 2; ++i)
#pragma unroll
        for (int j = 0; j < 4; ++j) acc[i][j] = MFMA16(a[i], b[j], acc[i][j]);
    }
#pragma unroll
    for (int i = 0; i < 2; ++i)
#pragma unroll
      for (int j = 0; j < 4; ++j)
#pragma unroll
        for (int r = 0; r < 4; ++r) {
          const int row = m0 + i * 16 + q * 4 + r;  // seq pos (h index)
          const int d = j * 16 + l;
          O[(size_t)(row * 256 + w) * 1024 + H * 64 + d] = f2b(acc[i][j][r] * rowinv[row]);
        }
  }
}

// ---------------- tied row attention dots, split-K over 8 chunks of 16 rows ----------------
__global__ __launch_bounds__(256) void row_dots(const unsigned short* __restrict__ C,
                                                float* __restrict__ dp) {
  const int H = blockIdx.z;
  const int r0 = blockIdx.y * 16;
  const int ti = blockIdx.x & 1, tj = blockIdx.x >> 1;
  const int tid = threadIdx.x, wave = tid >> 6, lane = tid & 63;
  const int q = lane >> 4, l = lane & 15;
  const int m0 = ti * 128 + (wave >> 1) * 64;
  const int n0 = tj * 128 + (wave & 1) * 64;
  const unsigned short* Qh = C + H * 64;
  const unsigned short* Kh = C + 512 + H * 64;
  f32x4 acc[4][4] = {};
  for (int ks = 0; ks < 32; ++ks) {
    const int k = ks * 32 + q * 8;
    const int rr = r0 + (k >> 6), d = k & 63;
    s16x8 a[4], b[4];
#pragma unroll
    for (int i = 0; i < 4; ++i)
      a[i] = *(const s16x8*)(Qh + (size_t)(rr * 256 + m0 + i * 16 + l) * PCOLS + d);
#pragma unroll
    for (int j = 0; j < 4; ++j)
      b[j] = *(const s16x8*)(Kh + (size_t)(rr * 256 + n0 + j * 16 + l) * PCOLS + d);
#pragma unroll
    for (int i = 0; i < 4; ++i)
#pragma unroll
      for (int j = 0; j < 4; ++j) acc[i][j] = MFMA16(a[i], b[j], acc[i][j]);
  }
  float* outp = dp + ((size_t)blockIdx.y * 8 + H) * 65536;
#pragma unroll
  for (int i = 0; i < 4; ++i)
#pragma unroll
    for (int j = 0; j < 4; ++j)
#pragma unroll
      for (int r = 0; r < 4; ++r)
        outp[(size_t)(m0 + i * 16 + q * 4 + r) * 256 + n0 + j * 16 + l] = acc[i][j][r];
}

__global__ __launch_bounds__(256) void row_softmax(const float* __restrict__ dp,
                                                   unsigned short* __restrict__ attn) {
  const int row = blockIdx.x;  // H*256 + i
  const int H = row >> 8, i = row & 255;
  const int t = threadIdx.x, wave = t >> 6, lane = t & 63;
  __shared__ float red[8];
  float v = 0.f;
#pragma unroll
  for (int c = 0; c < 8; ++c) v += dp[((size_t)c * 8 + H) * 65536 + (size_t)i * 256 + t];
  v *= 1.1048543456e-2f;  // 0.125 / sqrt(128)
  float m = v;
  for (int o = 32; o > 0; o >>= 1) m = fmaxf(m, __shfl_xor(m, o, 64));
  if (lane == 0) red[wave] = m;
  __syncthreads();
  const float M = fmaxf(fmaxf(red[0], red[1]), fmaxf(red[2], red[3]));
  const float e = __expf(v - M);
  float s = e;
  for (int o = 32; o > 0; o >>= 1) s += __shfl_xor(s, o, 64);
  if (lane == 0) red[4 + wave] = s;
  __syncthreads();
  const float S = red[4] + red[5] + red[6] + red[7];
  attn[(size_t)row * 256 + t] = f2b(e / S);
}

// ---------------- row attention PV: one block per (r, H) ----------------
__global__ __launch_bounds__(256) void row_pv(const unsigned short* __restrict__ C,
                                              const unsigned short* __restrict__ attn,
                                              unsigned short* __restrict__ O) {
  __shared__ unsigned short Vt[64 * 264];
  const int r = blockIdx.x, H = blockIdx.y;
  const int tid = threadIdx.x, wave = tid >> 6, lane = tid & 63;
  const int q = lane >> 4, l = lane & 15;
  const unsigned short* Vp = C + 1024 + H * 64;
  for (int u = tid; u < 2048; u += 256) {
    const int j = u >> 3, db = u & 7;
    s16x8 v = *(const s16x8*)(Vp + (size_t)(r * 256 + j) * PCOLS + db * 8);
#pragma unroll
    for (int t = 0; t < 8; ++t) Vt[(db * 8 + t) * 264 + j] = v[t];
  }
  __syncthreads();
  const unsigned short* A = attn + (size_t)H * 65536;
  const int m0 = wave * 64;
  f32x4 acc[4][4] = {};
#pragma unroll
  for (int ks = 0; ks < 8; ++ks) {
    const int kk = ks * 32 + q * 8;
    s16x8 a[4], b[4];
#pragma unroll
    for (int i = 0; i < 4; ++i) a[i] = *(const s16x8*)(A + (size_t)(m0 + i * 16 + l) * 256 + kk);
#pragma unroll
    for (int j = 0; j < 4; ++j) b[j] = *(const s16x8*)(&Vt[(j * 16 + l) * 264 + kk]);
#pragma unroll
    for (int i = 0; i < 4; ++i)
#pragma unroll
      for (int j = 0; j < 4; ++j) acc[i][j] = MFMA16(a[i], b[j], acc[i][j]);
  }
#pragma unroll
  for (int i = 0; i < 4; ++i)
#pragma unroll
    for (int j = 0; j < 4; ++j)
#pragma unroll
      for (int rr = 0; rr < 4; ++rr) {
        const int iw = m0 + i * 16 + q * 4 + rr;  // w index
        const int d = j * 16 + l;
        O[(size_t)(r * 256 + iw) * 1024 + 512 + H * 64 + d] = f2b(acc[i][j][rr]);
      }
}

// ---------------- output projection: out = Ocat(32768x1024) @ W2 + bias ----------------
__global__ __launch_bounds__(256) void out_proj(const unsigned short* __restrict__ O,
                                                const unsigned short* __restrict__ W2T,
                                                const float* __restrict__ bw,
                                                const float* __restrict__ bh,
                                                float* __restrict__ out) {
  const int tid = threadIdx.x, wave = tid >> 6, lane = tid & 63;
  const int q = lane >> 4, l = lane & 15;
  const int m0 = blockIdx.x * 128 + (wave >> 1) * 64;
  const int n0 = blockIdx.y * 128 + (wave & 1) * 64;
  f32x4 acc[4][4] = {};
  for (int ks = 0; ks < 32; ++ks) {
    const int kk = ks * 32 + q * 8;
    s16x8 a[4], b[4];
#pragma unroll
    for (int i = 0; i < 4; ++i) a[i] = *(const s16x8*)(O + (size_t)(m0 + i * 16 + l) * 1024 + kk);
#pragma unroll
    for (int j = 0; j < 4; ++j) b[j] = *(const s16x8*)(W2T + (size_t)(n0 + j * 16 + l) * 1024 + kk);
#pragma unroll
    for (int i = 0; i < 4; ++i)
#pragma unroll
      for (int j = 0; j < 4; ++j) acc[i][j] = MFMA16(a[i], b[j], acc[i][j]);
  }
#pragma unroll
  for (int i = 0; i < 4; ++i)
#pragma unroll
    for (int j = 0; j < 4; ++j) {
      const int col = n0 + j * 16 + l;
      const float bias = bw[col] + bh[col];
#pragma unroll
      for (int r = 0; r < 4; ++r)
        out[(size_t)(m0 + i * 16 + q * 4 + r) * 256 + col] = acc[i][j][r] + bias;
    }
}

extern "C" void kernel_launch(void* const* d_in, const int* in_sizes, int n_in,
                              void* d_out, int out_size, void* d_ws, size_t ws_size,
                              hipStream_t stream) {
  const float* x    = (const float*)d_in[0];
  const float* wq   = (const float*)d_in[1];
  const float* wkv  = (const float*)d_in[2];
  const float* wout = (const float*)d_in[3];
  const float* bw   = (const float*)d_in[4];
  const float* hq   = (const float*)d_in[5];
  const float* hkv  = (const float*)d_in[6];
  const float* hout = (const float*)d_in[7];
  const float* bh   = (const float*)d_in[8];
  float* out = (float*)d_out;

  char* ws = (char*)d_ws;
  unsigned short* x_bf  = (unsigned short*)(ws);               // 16 MB
  unsigned short* WcatT = (unsigned short*)(ws + 16777216);    // 1.5 MB
  unsigned short* W2T   = (unsigned short*)(ws + 18350080);    // 0.5 MB
  float*          dp    = (float*)(ws + 18874368);             // 16 MB (8 chunks x 8 H x 256 x 256 f32)
  unsigned short* attn  = (unsigned short*)(ws + 35651584);    // 1 MB
  unsigned short* Ocat  = (unsigned short*)(ws + 36700160);    // 64 MB
  unsigned short* Cproj = (unsigned short*)(ws + 103809024);   // 96 MB (reused per branch)
  // total 204,472,320 bytes

  cvt_x<<<8192, 256, 0, stream>>>(x, x_bf);
  build_wt<<<3072, 256, 0, stream>>>(wq, wkv, hq, hkv, WcatT);
  build_w2t<<<256, 256, 0, stream>>>(wout, hout, W2T);

  // w-branch
  gemm_proj<<<dim3(256, 12), 256, 0, stream>>>(x_bf, WcatT, Cproj);
  col_attn<<<dim3(256, 8), 256, 0, stream>>>(Cproj, Ocat);
  // h-branch (reuses Cproj)
  gemm_proj<<<dim3(256, 12), 256, 0, stream>>>(x_bf, WcatT + 1536 * 256, Cproj);
  row_dots<<<dim3(4, 8, 8), 256, 0, stream>>>(Cproj, dp);
  row_softmax<<<2048, 256, 0, stream>>>(dp, attn);
  row_pv<<<dim3(128, 8), 256, 0, stream>>>(Cproj, attn, Ocat);
  out_proj<<<dim3(256, 2), 256, 0, stream>>>(Ocat, W2T, bw, bh, out);
}

// Round 2
// 364.028 us; speedup vs baseline: 1.3546x; 1.3546x over previous
//
#include <hip/hip_runtime.h>

typedef short s16x8 __attribute__((ext_vector_type(8)));
typedef float f32x4 __attribute__((ext_vector_type(4)));

#define MFMA16(a, b, c) __builtin_amdgcn_mfma_f32_16x16x32_bf16((a), (b), (c), 0, 0, 0)

__device__ __forceinline__ unsigned short f2b(float f) {
  union { float f; unsigned int u; } v; v.f = f;
  unsigned int u = v.u;
  unsigned int r = (u + 0x7fffu + ((u >> 16) & 1u)) >> 16;  // RNE
  return (unsigned short)r;
}
__device__ __forceinline__ float b2f(unsigned short b) {
  union { unsigned int u; float f; } v; v.u = ((unsigned int)b) << 16;
  return v.f;
}

__device__ __forceinline__ void gld_lds16(const void* g, void* l) {
  __builtin_amdgcn_global_load_lds(
      (const __attribute__((address_space(1))) unsigned int*)g,
      (__attribute__((address_space(3))) unsigned int*)l, 16, 0, 0);
}

// ---------------- prep ----------------
__global__ __launch_bounds__(256) void cvt_x(const float* __restrict__ x,
                                             unsigned short* __restrict__ xb) {
  size_t i = ((size_t)blockIdx.x * 256 + threadIdx.x) * 4;
  float4 v = *(const float4*)(x + i);
  ushort4 o;
  o.x = f2b(v.x); o.y = f2b(v.y); o.z = f2b(v.z); o.w = f2b(v.w);
  *(ushort4*)(xb + i) = o;
}

// WcatT[n][k] = W[k][n], n in [0,3072): [wq | wkv | hq | hkv]
__global__ __launch_bounds__(256) void build_wt(const float* __restrict__ wq,
                                                const float* __restrict__ wkv,
                                                const float* __restrict__ hq,
                                                const float* __restrict__ hkv,
                                                unsigned short* __restrict__ WT) {
  const int n = blockIdx.x, k = threadIdx.x;
  float v;
  if (n < 512)       v = wq [(size_t)k * 512  + n];
  else if (n < 1536) v = wkv[(size_t)k * 1024 + (n - 512)];
  else if (n < 2048) v = hq [(size_t)k * 512  + (n - 1536)];
  else               v = hkv[(size_t)k * 1024 + (n - 2048)];
  WT[(size_t)n * 256 + k] = f2b(v);
}

// W2T[n][k] = [wout;hout][k][n], n<256, k<1024
__global__ __launch_bounds__(256) void build_w2t(const float* __restrict__ wout,
                                                 const float* __restrict__ hout,
                                                 unsigned short* __restrict__ W2T) {
  const int n = blockIdx.x;
  for (int k = threadIdx.x; k < 1024; k += 256) {
    const float v = (k < 512) ? wout[(size_t)k * 256 + n] : hout[(size_t)(k - 512) * 256 + n];
    W2T[(size_t)n * 1024 + k] = f2b(v);
  }
}

// ---------------- QKV projection with LDS staging ----------------
// C layout (per part q/k/v of 16777216 elems):
//   branch 0 (col attn): part + ((w*8+H)*128 + h)*64 + d     (slab = 128x64)
//   branch 1 (row attn): part + ((r*8+H)*256 + i)*64 + d     (slab = 256x64)
__global__ __launch_bounds__(256) void gemm_qkv(const unsigned short* __restrict__ X,
                                                const unsigned short* __restrict__ WT,
                                                unsigned short* __restrict__ C,
                                                int branch) {
  __shared__ unsigned short As[128 * 32];
  __shared__ unsigned short Bs[128 * 32];
  const int tid = threadIdx.x, wave = tid >> 6, lane = tid & 63;
  const int q = lane >> 4, l = lane & 15;
  const int m0 = blockIdx.x * 128;
  const int n0 = blockIdx.y * 128;
  const int mt = (wave >> 1) * 64;  // wave tile row in block
  const int nt = (wave & 1) * 64;
  const char* Xb = (const char*)X;
  const char* Wb = (const char*)WT;
  const int srow = wave * 32 + (lane >> 2);  // staging row (+c*16)
  const int sboff = (lane & 3) * 16;         // byte offset within 64-B row chunk
  char* AsB = (char*)As;
  char* BsB = (char*)Bs;
  f32x4 acc[4][4] = {};
#pragma unroll
  for (int ks = 0; ks < 8; ++ks) {
    const int kb = ks * 64;  // byte offset of k-chunk within 512-B row
    gld_lds16(Xb + (size_t)(m0 + srow) * 512 + kb + sboff, AsB + wave * 2048);
    gld_lds16(Xb + (size_t)(m0 + srow + 16) * 512 + kb + sboff, AsB + wave * 2048 + 1024);
    gld_lds16(Wb + (size_t)(n0 + srow) * 512 + kb + sboff, BsB + wave * 2048);
    gld_lds16(Wb + (size_t)(n0 + srow + 16) * 512 + kb + sboff, BsB + wave * 2048 + 1024);
    __syncthreads();
    s16x8 a[4], b[4];
#pragma unroll
    for (int i = 0; i < 4; ++i) a[i] = *(const s16x8*)(&As[(mt + i * 16 + l) * 32 + q * 8]);
#pragma unroll
    for (int j = 0; j < 4; ++j) b[j] = *(const s16x8*)(&Bs[(nt + j * 16 + l) * 32 + q * 8]);
#pragma unroll
    for (int i = 0; i < 4; ++i)
#pragma unroll
      for (int j = 0; j < 4; ++j) acc[i][j] = MFMA16(a[i], b[j], acc[i][j]);
    __syncthreads();
  }
#pragma unroll
  for (int i = 0; i < 4; ++i)
#pragma unroll
    for (int j = 0; j < 4; ++j) {
      const int col = n0 + nt + j * 16 + l;
      const int part = col >> 9, H = (col & 511) >> 6, d = col & 63;
      unsigned short* base = C + (size_t)part * 16777216;
#pragma unroll
      for (int r = 0; r < 4; ++r) {
        const int m = m0 + mt + i * 16 + q * 4 + r;
        size_t idx;
        if (branch == 0) idx = ((size_t)((m & 255) * 8 + H) * 128 + (m >> 8)) * 64 + d;
        else             idx = ((size_t)((m >> 8) * 8 + H) * 256 + (m & 255)) * 64 + d;
        base[idx] = f2b(acc[i][j][r]);
      }
    }
}

// ---------------- column attention: one block per (w, H) ----------------
__global__ __launch_bounds__(256) void col_attn(const unsigned short* __restrict__ C,
                                                unsigned short* __restrict__ O) {
  __shared__ unsigned short Sp[128 * 136];  // logits -> P (bf16)
  __shared__ unsigned short Vt[64 * 136];   // V^T
  __shared__ float rowinv[128];
  const int w = blockIdx.x, H = blockIdx.y;
  const int tid = threadIdx.x, wave = tid >> 6, lane = tid & 63;
  const int q = lane >> 4, l = lane & 15;
  const size_t slab = (size_t)(w * 8 + H) * 8192;  // 128x64
  const unsigned short* Qs = C + slab;
  const unsigned short* Ks = C + 16777216 + slab;
  const unsigned short* Vs = C + 33554432 + slab;
  // stage V^T: Vt[d][j] = V[j][d]
  for (int u = tid; u < 1024; u += 256) {
    const int j = u >> 3, db = u & 7;
    s16x8 v = *(const s16x8*)(Vs + j * 64 + db * 8);
#pragma unroll
    for (int t = 0; t < 8; ++t) Vt[(db * 8 + t) * 136 + j] = v[t];
  }
  // S = q k^T * scale; wave handles 32 rows
  {
    const int m0 = wave * 32;
    f32x4 acc[2][8] = {};
#pragma unroll
    for (int ks = 0; ks < 2; ++ks) {
      const int kk = ks * 32 + q * 8;
      s16x8 a[2], b[8];
#pragma unroll
      for (int i = 0; i < 2; ++i) a[i] = *(const s16x8*)(Qs + (m0 + i * 16 + l) * 64 + kk);
#pragma unroll
      for (int j = 0; j < 8; ++j) b[j] = *(const s16x8*)(Ks + (j * 16 + l) * 64 + kk);
#pragma unroll
      for (int i = 0; i < 2; ++i)
#pragma unroll
        for (int j = 0; j < 8; ++j) acc[i][j] = MFMA16(a[i], b[j], acc[i][j]);
    }
#pragma unroll
    for (int i = 0; i < 2; ++i)
#pragma unroll
      for (int j = 0; j < 8; ++j)
#pragma unroll
        for (int r = 0; r < 4; ++r)
          Sp[(m0 + i * 16 + q * 4 + r) * 136 + j * 16 + l] = f2b(acc[i][j][r] * 0.125f);
  }
  __syncthreads();
  // softmax per row (unnormalized P in LDS; 1/sum folded into epilogue)
  if (tid < 128) {
    float mx = -1e30f;
    for (int j = 0; j < 128; ++j) mx = fmaxf(mx, b2f(Sp[tid * 136 + j]));
    float s = 0.f;
    for (int j = 0; j < 128; ++j) {
      float e = __expf(b2f(Sp[tid * 136 + j]) - mx);
      s += e;
      Sp[tid * 136 + j] = f2b(e);
    }
    rowinv[tid] = 1.0f / s;
  }
  __syncthreads();
  // O = P @ V
  {
    const int m0 = wave * 32;
    f32x4 acc[2][4] = {};
#pragma unroll
    for (int ks = 0; ks < 4; ++ks) {
      const int kk = ks * 32 + q * 8;
      s16x8 a[2], b[4];
#pragma unroll
      for (int i = 0; i < 2; ++i) a[i] = *(const s16x8*)(&Sp[(m0 + i * 16 + l) * 136 + kk]);
#pragma unroll
      for (int j = 0; j < 4; ++j) b[j] = *(const s16x8*)(&Vt[(j * 16 + l) * 136 + kk]);
#pragma unroll
      for (int i = 0; i < 2; ++i)
#pragma unroll
        for (int j = 0; j < 4; ++j) acc[i][j] = MFMA16(a[i], b[j], acc[i][j]);
    }
#pragma unroll
    for (int i = 0; i < 2; ++i)
#pragma unroll
      for (int j = 0; j < 4; ++j)
#pragma unroll
        for (int r = 0; r < 4; ++r) {
          const int row = m0 + i * 16 + q * 4 + r;  // seq pos (h index)
          const int d = j * 16 + l;
          O[(size_t)(row * 256 + w) * 1024 + H * 64 + d] = f2b(acc[i][j][r] * rowinv[row]);
        }
  }
}

// ---------------- tied row attention dots, split-K over 8 chunks of 16 rows ----------------
__global__ __launch_bounds__(256) void row_dots(const unsigned short* __restrict__ C,
                                                float* __restrict__ dp) {
  const int H = blockIdx.z;
  const int r0 = blockIdx.y * 16;
  const int ti = blockIdx.x & 1, tj = blockIdx.x >> 1;
  const int tid = threadIdx.x, wave = tid >> 6, lane = tid & 63;
  const int q = lane >> 4, l = lane & 15;
  const int m0 = ti * 128 + (wave >> 1) * 64;
  const int n0 = tj * 128 + (wave & 1) * 64;
  const unsigned short* Qh = C;
  const unsigned short* Kh = C + 16777216;
  f32x4 acc[4][4] = {};
  for (int ks = 0; ks < 32; ++ks) {
    const int k = ks * 32 + q * 8;
    const int rr = r0 + (k >> 6), d = k & 63;
    const size_t slab = (size_t)(rr * 8 + H) * 16384;  // 256x64
    s16x8 a[4], b[4];
#pragma unroll
    for (int i = 0; i < 4; ++i) a[i] = *(const s16x8*)(Qh + slab + (m0 + i * 16 + l) * 64 + d);
#pragma unroll
    for (int j = 0; j < 4; ++j) b[j] = *(const s16x8*)(Kh + slab + (n0 + j * 16 + l) * 64 + d);
#pragma unroll
    for (int i = 0; i < 4; ++i)
#pragma unroll
      for (int j = 0; j < 4; ++j) acc[i][j] = MFMA16(a[i], b[j], acc[i][j]);
  }
  float* outp = dp + ((size_t)blockIdx.y * 8 + H) * 65536;
#pragma unroll
  for (int i = 0; i < 4; ++i)
#pragma unroll
    for (int j = 0; j < 4; ++j)
#pragma unroll
      for (int r = 0; r < 4; ++r)
        outp[(size_t)(m0 + i * 16 + q * 4 + r) * 256 + n0 + j * 16 + l] = acc[i][j][r];
}

__global__ __launch_bounds__(256) void row_softmax(const float* __restrict__ dp,
                                                   unsigned short* __restrict__ attn) {
  const int row = blockIdx.x;  // H*256 + i
  const int H = row >> 8, i = row & 255;
  const int t = threadIdx.x, wave = t >> 6, lane = t & 63;
  __shared__ float red[8];
  float v = 0.f;
#pragma unroll
  for (int c = 0; c < 8; ++c) v += dp[((size_t)c * 8 + H) * 65536 + (size_t)i * 256 + t];
  v *= 1.1048543456e-2f;  // 0.125 / sqrt(128)
  float m = v;
  for (int o = 32; o > 0; o >>= 1) m = fmaxf(m, __shfl_xor(m, o, 64));
  if (lane == 0) red[wave] = m;
  __syncthreads();
  const float M = fmaxf(fmaxf(red[0], red[1]), fmaxf(red[2], red[3]));
  const float e = __expf(v - M);
  float s = e;
  for (int o = 32; o > 0; o >>= 1) s += __shfl_xor(s, o, 64);
  if (lane == 0) red[4 + wave] = s;
  __syncthreads();
  const float S = red[4] + red[5] + red[6] + red[7];
  attn[(size_t)row * 256 + t] = f2b(e / S);
}

// ---------------- row attention PV: one block per (r, H) ----------------
__global__ __launch_bounds__(256) void row_pv(const unsigned short* __restrict__ C,
                                              const unsigned short* __restrict__ attn,
                                              unsigned short* __restrict__ O) {
  __shared__ unsigned short Vt[64 * 264];
  const int r = blockIdx.x, H = blockIdx.y;
  const int tid = threadIdx.x, wave = tid >> 6, lane = tid & 63;
  const int q = lane >> 4, l = lane & 15;
  const unsigned short* Vs = C + 33554432 + (size_t)(r * 8 + H) * 16384;
  for (int u = tid; u < 2048; u += 256) {
    const int j = u >> 3, db = u & 7;
    s16x8 v = *(const s16x8*)(Vs + j * 64 + db * 8);
#pragma unroll
    for (int t = 0; t < 8; ++t) Vt[(db * 8 + t) * 264 + j] = v[t];
  }
  __syncthreads();
  const unsigned short* A = attn + (size_t)H * 65536;
  const int m0 = wave * 64;
  f32x4 acc[4][4] = {};
#pragma unroll
  for (int ks = 0; ks < 8; ++ks) {
    const int kk = ks * 32 + q * 8;
    s16x8 a[4], b[4];
#pragma unroll
    for (int i = 0; i < 4; ++i) a[i] = *(const s16x8*)(A + (size_t)(m0 + i * 16 + l) * 256 + kk);
#pragma unroll
    for (int j = 0; j < 4; ++j) b[j] = *(const s16x8*)(&Vt[(j * 16 + l) * 264 + kk]);
#pragma unroll
    for (int i = 0; i < 4; ++i)
#pragma unroll
      for (int j = 0; j < 4; ++j) acc[i][j] = MFMA16(a[i], b[j], acc[i][j]);
  }
#pragma unroll
  for (int i = 0; i < 4; ++i)
#pragma unroll
    for (int j = 0; j < 4; ++j)
#pragma unroll
      for (int rr = 0; rr < 4; ++rr) {
        const int iw = m0 + i * 16 + q * 4 + rr;  // w index
        const int d = j * 16 + l;
        O[(size_t)(r * 256 + iw) * 1024 + 512 + H * 64 + d] = f2b(acc[i][j][rr]);
      }
}

// ---------------- output projection with LDS staging: out = Ocat(32768x1024) @ W2 + bias ----------------
__global__ __launch_bounds__(256) void out_proj(const unsigned short* __restrict__ O,
                                                const unsigned short* __restrict__ W2T,
                                                const float* __restrict__ bw,
                                                const float* __restrict__ bh,
                                                float* __restrict__ out) {
  __shared__ unsigned short As[128 * 32];
  __shared__ unsigned short Bs[128 * 32];
  const int tid = threadIdx.x, wave = tid >> 6, lane = tid & 63;
  const int q = lane >> 4, l = lane & 15;
  const int m0 = blockIdx.x * 128;
  const int n0 = blockIdx.y * 128;
  const int mt = (wave >> 1) * 64;
  const int nt = (wave & 1) * 64;
  const char* Ob = (const char*)O;
  const char* Wb = (const char*)W2T;
  const int srow = wave * 32 + (lane >> 2);
  const int sboff = (lane & 3) * 16;
  char* AsB = (char*)As;
  char* BsB = (char*)Bs;
  f32x4 acc[4][4] = {};
  for (int ks = 0; ks < 32; ++ks) {
    const int kb = ks * 64;  // byte offset within 2048-B row
    gld_lds16(Ob + (size_t)(m0 + srow) * 2048 + kb + sboff, AsB + wave * 2048);
    gld_lds16(Ob + (size_t)(m0 + srow + 16) * 2048 + kb + sboff, AsB + wave * 2048 + 1024);
    gld_lds16(Wb + (size_t)(n0 + srow) * 2048 + kb + sboff, BsB + wave * 2048);
    gld_lds16(Wb + (size_t)(n0 + srow + 16) * 2048 + kb + sboff, BsB + wave * 2048 + 1024);
    __syncthreads();
    s16x8 a[4], b[4];
#pragma unroll
    for (int i = 0; i < 4; ++i) a[i] = *(const s16x8*)(&As[(mt + i * 16 + l) * 32 + q * 8]);
#pragma unroll
    for (int j = 0; j < 4; ++j) b[j] = *(const s16x8*)(&Bs[(nt + j * 16 + l) * 32 + q * 8]);
#pragma unroll
    for (int i = 0; i < 4; ++i)
#pragma unroll
      for (int j = 0; j < 4; ++j) acc[i][j] = MFMA16(a[i], b[j], acc[i][j]);
    __syncthreads();
  }
#pragma unroll
  for (int i = 0; i < 4; ++i)
#pragma unroll
    for (int j = 0; j < 4; ++j) {
      const int col = n0 + nt + j * 16 + l;
      const float bias = bw[col] + bh[col];
#pragma unroll
      for (int r = 0; r < 4; ++r)
        out[(size_t)(m0 + mt + i * 16 + q * 4 + r) * 256 + col] = acc[i][j][r] + bias;
    }
}

extern "C" void kernel_launch(void* const* d_in, const int* in_sizes, int n_in,
                              void* d_out, int out_size, void* d_ws, size_t ws_size,
                              hipStream_t stream) {
  const float* x    = (const float*)d_in[0];
  const float* wq   = (const float*)d_in[1];
  const float* wkv  = (const float*)d_in[2];
  const float* wout = (const float*)d_in[3];
  const float* bw   = (const float*)d_in[4];
  const float* hq   = (const float*)d_in[5];
  const float* hkv  = (const float*)d_in[6];
  const float* hout = (const float*)d_in[7];
  const float* bh   = (const float*)d_in[8];
  float* out = (float*)d_out;

  char* ws = (char*)d_ws;
  unsigned short* x_bf  = (unsigned short*)(ws);               // 16 MB
  unsigned short* WcatT = (unsigned short*)(ws + 16777216);    // 1.5 MB
  unsigned short* W2T   = (unsigned short*)(ws + 18350080);    // 0.5 MB
  float*          dp    = (float*)(ws + 18874368);             // 16 MB
  unsigned short* attn  = (unsigned short*)(ws + 35651584);    // 1 MB
  unsigned short* Ocat  = (unsigned short*)(ws + 36700160);    // 64 MB
  unsigned short* Cproj = (unsigned short*)(ws + 103809024);   // 96 MB (reused per branch)

  cvt_x<<<8192, 256, 0, stream>>>(x, x_bf);
  build_wt<<<3072, 256, 0, stream>>>(wq, wkv, hq, hkv, WcatT);
  build_w2t<<<256, 256, 0, stream>>>(wout, hout, W2T);

  // w-branch (column attention)
  gemm_qkv<<<dim3(256, 12), 256, 0, stream>>>(x_bf, WcatT, Cproj, 0);
  col_attn<<<dim3(256, 8), 256, 0, stream>>>(Cproj, Ocat);
  // h-branch (tied row attention), reuses Cproj
  gemm_qkv<<<dim3(256, 12), 256, 0, stream>>>(x_bf, WcatT + 1536 * 256, Cproj, 1);
  row_dots<<<dim3(4, 8, 8), 256, 0, stream>>>(Cproj, dp);
  row_softmax<<<2048, 256, 0, stream>>>(dp, attn);
  row_pv<<<dim3(128, 8), 256, 0, stream>>>(Cproj, attn, Ocat);
  out_proj<<<dim3(256, 2), 256, 0, stream>>>(Ocat, W2T, bw, bh, out);
}